// Round 1
// baseline (518.944 us; speedup 1.0000x reference)
//
#include <hip/hip_runtime.h>
#include <hip/hip_bf16.h>
#include <stdint.h>

#define N_ROWS 200000
#define C_DIM  128
#define TAPS   27
#define EPS    1e-5f

typedef __attribute__((ext_vector_type(8)))  short  short8;
typedef __attribute__((ext_vector_type(16))) float  floatx16;

__device__ __forceinline__ unsigned int f2bf(float f) {
  union { float f; unsigned int u; } v; v.f = f;
  unsigned int r = v.u + 0x7FFFu + ((v.u >> 16) & 1u);   // RNE, inputs finite
  return r >> 16;
}

__device__ __forceinline__ void glds16(const unsigned short* g, unsigned short* l) {
  __builtin_amdgcn_global_load_lds(
      (const __attribute__((address_space(1))) unsigned int*)g,
      (__attribute__((address_space(3))) unsigned int*)l, 16, 0, 0);
}

// ---------------- feats fp32 -> bf16 ----------------
__global__ __launch_bounds__(256) void k_cast(const float* __restrict__ in,
                                              unsigned short* __restrict__ out, int n8) {
  int i = blockIdx.x * 256 + threadIdx.x;
  if (i >= n8) return;
  const float4* p = (const float4*)in + (size_t)i * 2;
  float4 a = p[0], b = p[1];
  uint4 v;
  v.x = f2bf(a.x) | (f2bf(a.y) << 16);
  v.y = f2bf(a.z) | (f2bf(a.w) << 16);
  v.z = f2bf(b.x) | (f2bf(b.y) << 16);
  v.w = f2bf(b.z) | (f2bf(b.w) << 16);
  *(uint4*)(out + (size_t)i * 8) = v;
}

// ---- fold Linear into conv weights; emit MFMA B-fragment layout ----
// wfrag[k][nt(4)][s(8)][lane(64)][j(8)] (bf16):
//   B frag of mfma_f32_32x32x16_bf16: lane holds B[kk=(l>>5)*8+j][n=l&31]
//   kk_global = s*16 + (l>>5)*8 + j ; co = nt*32 + (l&31)
// lin_w staged in LDS transposed + XOR-swizzled: lwT[t][co ^ (t&31)]
__global__ __launch_bounds__(256) void k_fold(const float* __restrict__ conv_w,
                                              const float* __restrict__ lin_w,
                                              const float* __restrict__ conv_b,
                                              const float* __restrict__ lin_b,
                                              unsigned short* __restrict__ wfrag,
                                              float* __restrict__ biasf) {
  __shared__ float lwT[128 * 128];  // 64 KB
  for (int e = threadIdx.x; e < 16384; e += 256) {
    int co = e >> 7, t = e & 127;
    lwT[t * 128 + (co ^ (t & 31))] = lin_w[e];
  }
  __syncthreads();

  int id = blockIdx.x * 256 + threadIdx.x;
  const int NW = TAPS * 4 * 8 * 64;  // 55296
  if (id < NW) {
    int l  = id & 63;
    int s  = (id >> 6) & 7;
    int nt = (id >> 9) & 3;
    int k  = id >> 11;
    int ci0 = s * 16 + (l >> 5) * 8;
    int co  = nt * 32 + (l & 31);
    const float* cw = conv_w + ((size_t)(k * 128 + ci0)) * 128;
    float acc[8] = {0, 0, 0, 0, 0, 0, 0, 0};
    for (int t = 0; t < 128; ++t) {
      float lv = lwT[t * 128 + (co ^ (t & 31))];
#pragma unroll
      for (int j = 0; j < 8; ++j) acc[j] += cw[j * 128 + t] * lv;
    }
    uint4 v;
    v.x = f2bf(acc[0]) | (f2bf(acc[1]) << 16);
    v.y = f2bf(acc[2]) | (f2bf(acc[3]) << 16);
    v.z = f2bf(acc[4]) | (f2bf(acc[5]) << 16);
    v.w = f2bf(acc[6]) | (f2bf(acc[7]) << 16);
    *(uint4*)(wfrag + (size_t)id * 8) = v;
  } else if (id < NW + 128) {
    int co = id - NW;
    float s = lin_b[co];
    for (int t = 0; t < 128; ++t) s += conv_b[t] * lwT[t * 128 + (co ^ (t & 31))];
    biasf[co] = s;
  }
}

// ---------------- fused gather-GEMM + LayerNorm ----------------
// 512 thr = 8 waves; wave w owns rows [blk*256 + w*32, +32), ALL 128 cols.
// A: global->register gather, software-pipelined ONE TAP AHEAD with in-place
//    register rotation (issue a_s(k+1) right after the MFMAs consuming a_s(k)).
// B: LDS double-buffer via global_load_lds, 1-tap lookahead.
// Sync: raw s_barrier + uniform counted vmcnt(8). FIFO at the wait is
//   worst-case [B(k)x4, nid, a0..a7(k), B(k+1)x4] = 17 outstanding; vmcnt(8)
//   retires B(k)+nid+a0..a3 (all consumed immediately after the barrier) and
//   leaves a4..a7(k) + B(k+1) glds in flight across the barrier (never drain
//   to 0 in the main loop). sched_barrier(0) pins issue order at the two
//   count-critical points. Index stream is pipelined 2 taps deep.
// LayerNorm fully in-wave. No __syncthreads anywhere.

#define STEP_LD(s, av)                                                       \
  {                                                                          \
    short8 b0 = *(const short8*)(bb + (0 * 8 + s) * 512);                    \
    short8 b1 = *(const short8*)(bb + (1 * 8 + s) * 512);                    \
    short8 b2 = *(const short8*)(bb + (2 * 8 + s) * 512);                    \
    short8 b3 = *(const short8*)(bb + (3 * 8 + s) * 512);                    \
    acc0 = __builtin_amdgcn_mfma_f32_32x32x16_bf16(av, b0, acc0, 0, 0, 0);   \
    acc1 = __builtin_amdgcn_mfma_f32_32x32x16_bf16(av, b1, acc1, 0, 0, 0);   \
    acc2 = __builtin_amdgcn_mfma_f32_32x32x16_bf16(av, b2, acc2, 0, 0, 0);   \
    acc3 = __builtin_amdgcn_mfma_f32_32x32x16_bf16(av, b3, acc3, 0, 0, 0);   \
    av = apn[s * 2];                                                         \
  }

#define STEP_NL(s, av)                                                       \
  {                                                                          \
    short8 b0 = *(const short8*)(bb + (0 * 8 + s) * 512);                    \
    short8 b1 = *(const short8*)(bb + (1 * 8 + s) * 512);                    \
    short8 b2 = *(const short8*)(bb + (2 * 8 + s) * 512);                    \
    short8 b3 = *(const short8*)(bb + (3 * 8 + s) * 512);                    \
    acc0 = __builtin_amdgcn_mfma_f32_32x32x16_bf16(av, b0, acc0, 0, 0, 0);   \
    acc1 = __builtin_amdgcn_mfma_f32_32x32x16_bf16(av, b1, acc1, 0, 0, 0);   \
    acc2 = __builtin_amdgcn_mfma_f32_32x32x16_bf16(av, b2, acc2, 0, 0, 0);   \
    acc3 = __builtin_amdgcn_mfma_f32_32x32x16_bf16(av, b3, acc3, 0, 0, 0);   \
  }

__global__ __launch_bounds__(512, 4) void k_main(const unsigned short* __restrict__ featsB,
                                                 const int* __restrict__ nidx,
                                                 const unsigned short* __restrict__ wfrag,
                                                 const float* __restrict__ biasf,
                                                 const float* __restrict__ lnw,
                                                 const float* __restrict__ lnb,
                                                 float* __restrict__ out) {
  __shared__ unsigned short ldsB[2][16384];  // 2 x 32 KB

  const int tid = threadIdx.x;
  const int l   = tid & 63;
  const int w   = tid >> 6;
  const int l31 = l & 31;
  const int lh  = l >> 5;
  const int row0w = blockIdx.x * 256 + w * 32;
  const int gr  = row0w + l31;
  const int grc = (gr < N_ROWS) ? gr : 0;
  const int* np = nidx + (size_t)grc * TAPS;

  floatx16 acc0 = {0.f}, acc1 = {0.f}, acc2 = {0.f}, acc3 = {0.f};

  // index pipeline (2 taps deep): nid0 feeds the prologue A(0) gather;
  // nidB always holds the rows for the NEXT tap's in-loop A issues.
  int nid0 = np[0];
  int nidB = np[1];

  // prologue: stage B(0) into buf0
  {
    const unsigned short* src = wfrag + (size_t)tid * 8;
    unsigned short* dst = &ldsB[0][w * 512];
#pragma unroll
    for (int r = 0; r < 4; ++r) glds16(src + r * 4096, dst + r * 4096);
  }

  // prologue: issue A(0) gather into registers (overlaps B(0) staging)
  short8 a0, a1, a2, a3, a4, a5, a6, a7;
  {
    const short8* ap = (const short8*)(featsB + (size_t)(unsigned)nid0 * 128 + lh * 8);
    a0 = ap[0];  a1 = ap[2];  a2 = ap[4];  a3 = ap[6];
    a4 = ap[8];  a5 = ap[10]; a6 = ap[12]; a7 = ap[14];
  }

  for (int k = 0; k < TAPS - 1; ++k) {
    const int cur = k & 1;
    // stage B(k+1) into the other buffer (all waves passed end-of-iter
    // barrier of k-1, so buf[cur^1] is free)
    {
      const unsigned short* src = wfrag + (size_t)(k + 1) * 16384 + (size_t)tid * 8;
      unsigned short* dst = &ldsB[cur ^ 1][w * 512];
#pragma unroll
      for (int r = 0; r < 4; ++r) glds16(src + r * 4096, dst + r * 4096);
    }
    __builtin_amdgcn_sched_barrier(0);   // pin: glds issued above the count
    __builtin_amdgcn_s_waitcnt(0xF78);   // vmcnt(8): B(k) landed; a4..a7(k)
                                         // + B(k+1) stay in flight
    __builtin_amdgcn_s_barrier();        // raw: no compiler vmcnt(0) drain

    // index prefetch for tap k+2 (consumed next iteration)
    int nidC = np[(k + 2 < TAPS) ? (k + 2) : (TAPS - 1)];
    // base for next-tap A issues (rows nidB = np[k+1])
    const short8* apn = (const short8*)(featsB + (size_t)(unsigned)nidB * 128 + lh * 8);
    const unsigned short* bb = &ldsB[cur][l * 8];

    STEP_LD(0, a0) STEP_LD(1, a1) STEP_LD(2, a2) STEP_LD(3, a3)
    STEP_LD(4, a4) STEP_LD(5, a5) STEP_LD(6, a6) STEP_LD(7, a7)

    __builtin_amdgcn_sched_barrier(0);   // pin: A issues stay in this phase
    __builtin_amdgcn_s_barrier();        // all reads of buf[cur] done
    nidB = nidC;
  }

  // tap 26 (peeled: no prefetch issues)
  {
    __builtin_amdgcn_s_waitcnt(0xF78);   // B(26) landed (only A(26) newer)
    __builtin_amdgcn_s_barrier();
    const unsigned short* bb = &ldsB[(TAPS - 1) & 1][l * 8];
    STEP_NL(0, a0) STEP_NL(1, a1) STEP_NL(2, a2) STEP_NL(3, a3)
    STEP_NL(4, a4) STEP_NL(5, a5) STEP_NL(6, a6) STEP_NL(7, a7)
  }

  // ---- epilogue: bias + in-wave LayerNorm + store ----
  float b0 = biasf[l31], b1 = biasf[32 + l31], b2 = biasf[64 + l31], b3 = biasf[96 + l31];
  float g0 = lnw[l31],   g1 = lnw[32 + l31],   g2 = lnw[64 + l31],   g3 = lnw[96 + l31];
  float c0 = lnb[l31],   c1 = lnb[32 + l31],   c2 = lnb[64 + l31],   c3 = lnb[96 + l31];

#pragma unroll
  for (int r = 0; r < 16; ++r) {
    float x0 = acc0[r] + b0, x1 = acc1[r] + b1, x2 = acc2[r] + b2, x3 = acc3[r] + b3;
    float s = x0 + x1 + x2 + x3;
    float q = x0 * x0 + x1 * x1 + x2 * x2 + x3 * x3;
#pragma unroll
    for (int off = 16; off >= 1; off >>= 1) {
      s += __shfl_xor(s, off, 64);
      q += __shfl_xor(q, off, 64);
    }
    float mu  = s * (1.0f / 128.0f);
    float var = q * (1.0f / 128.0f) - mu * mu;
    float rs  = rsqrtf(var + EPS);
    int row   = (r & 3) + 8 * (r >> 2) + 4 * lh;  // 32x32 C/D row map
    int grow  = row0w + row;
    if (grow < N_ROWS) {
      float* o = out + (size_t)grow * 128;
      o[l31]      = (x0 - mu) * rs * g0 + c0;
      o[32 + l31] = (x1 - mu) * rs * g1 + c1;
      o[64 + l31] = (x2 - mu) * rs * g2 + c2;
      o[96 + l31] = (x3 - mu) * rs * g3 + c3;
    }
  }
}

extern "C" void kernel_launch(void* const* d_in, const int* in_sizes, int n_in,
                              void* d_out, int out_size, void* d_ws, size_t ws_size,
                              hipStream_t stream) {
  const float* feats  = (const float*)d_in[0];
  const int*   nidx   = (const int*)d_in[1];
  const float* conv_w = (const float*)d_in[2];
  const float* conv_b = (const float*)d_in[3];
  const float* lin_w  = (const float*)d_in[4];
  const float* lin_b  = (const float*)d_in[5];
  const float* ln_w   = (const float*)d_in[6];
  const float* ln_b   = (const float*)d_in[7];
  float* out = (float*)d_out;

  unsigned short* featsB = (unsigned short*)d_ws;                       // 51,200,000 B
  unsigned short* wfrag  = (unsigned short*)((char*)d_ws + 51200000);   //    884,736 B
  float*          biasf  = (float*)((char*)d_ws + 51200000 + 884736);   //        512 B

  int n8 = N_ROWS * C_DIM / 8;  // 3,200,000
  k_cast<<<(n8 + 255) / 256, 256, 0, stream>>>(feats, featsB, n8);
  k_fold<<<(TAPS * 2048 + 128 + 255) / 256, 256, 0, stream>>>(conv_w, lin_w, conv_b, lin_b,
                                                              wfrag, biasf);
  k_main<<<(N_ROWS + 255) / 256, 512, 0, stream>>>(featsB, nidx, wfrag, biasf, ln_w, ln_b, out);
}

// Round 3
// 511.747 us; speedup vs baseline: 1.0141x; 1.0141x over previous
//
#include <hip/hip_runtime.h>
#include <hip/hip_bf16.h>
#include <stdint.h>

#define N_ROWS 200000
#define C_DIM  128
#define TAPS   27
#define EPS    1e-5f

typedef __attribute__((ext_vector_type(8)))  short  short8;
typedef __attribute__((ext_vector_type(16))) float  floatx16;

// ---- gather path: sc0 (L1-bypass) buffer loads if builtins available ----
// NOTE (r2): on this ROCm, raw_buffer_load_b128 takes __amdgpu_buffer_rsrc_t
// (proven by r1 compile error); construct it with make_buffer_rsrc.
#if __has_builtin(__builtin_amdgcn_make_buffer_rsrc) && __has_builtin(__builtin_amdgcn_raw_buffer_load_b128)
#define GATHER_SC0 1
#else
#define GATHER_SC0 0
#endif

__device__ __forceinline__ unsigned int f2bf(float f) {
  union { float f; unsigned int u; } v; v.f = f;
  unsigned int r = v.u + 0x7FFFu + ((v.u >> 16) & 1u);   // RNE, inputs finite
  return r >> 16;
}

__device__ __forceinline__ void glds16(const unsigned short* g, unsigned short* l) {
  __builtin_amdgcn_global_load_lds(
      (const __attribute__((address_space(1))) unsigned int*)g,
      (__attribute__((address_space(3))) unsigned int*)l, 16, 0, 0);
}

#if GATHER_SC0
__device__ __forceinline__ short8 ld16sc0(__amdgpu_buffer_rsrc_t r, int voff) {
  // aux=1 -> sc0 (GLC): no L1 allocation; L2 caching unchanged. Goal: gather
  // line concurrency not clamped by per-CU L1 miss slots.
  return __builtin_bit_cast(short8,
      __builtin_amdgcn_raw_buffer_load_b128(r, voff, 0, 1));
}
#endif

// ---------------- feats fp32 -> bf16 ----------------
__global__ __launch_bounds__(256) void k_cast(const float* __restrict__ in,
                                              unsigned short* __restrict__ out, int n8) {
  int i = blockIdx.x * 256 + threadIdx.x;
  if (i >= n8) return;
  const float4* p = (const float4*)in + (size_t)i * 2;
  float4 a = p[0], b = p[1];
  uint4 v;
  v.x = f2bf(a.x) | (f2bf(a.y) << 16);
  v.y = f2bf(a.z) | (f2bf(a.w) << 16);
  v.z = f2bf(b.x) | (f2bf(b.y) << 16);
  v.w = f2bf(b.z) | (f2bf(b.w) << 16);
  *(uint4*)(out + (size_t)i * 8) = v;
}

// ---------------- nidx [N][27] -> nidxT [27][N] ----------------
// 64-row tiles: 64*27 = 1728 ints contiguous in, coalesced out per tap.
__global__ __launch_bounds__(256) void k_tr(const int* __restrict__ in,
                                            int* __restrict__ outT) {
  __shared__ int t[1728];
  const int tile = blockIdx.x;                 // 3125 tiles x 64 rows (exact)
  const int* src = in + (size_t)tile * 1728;
  for (int e = threadIdx.x; e < 1728; e += 256) t[e] = src[e];
  __syncthreads();
  const int base = tile * 64;
  for (int o = threadIdx.x; o < 1728; o += 256) {
    int k = o >> 6, r = o & 63;                // stride-27 LDS read: gcd(27,32)=1, conflict-free
    outT[(size_t)k * N_ROWS + base + r] = t[r * 27 + k];
  }
}

// ---- fold Linear into conv weights; emit MFMA B-fragment layout ----
// wfrag[k][nt(4)][s(8)][lane(64)][j(8)] (bf16):
//   B frag of mfma_f32_32x32x16_bf16: lane holds B[kk=(l>>5)*8+j][n=l&31]
//   kk_global = s*16 + (l>>5)*8 + j ; co = nt*32 + (l&31)
// lin_w staged in LDS transposed + XOR-swizzled: lwT[t][co ^ (t&31)]
__global__ __launch_bounds__(256) void k_fold(const float* __restrict__ conv_w,
                                              const float* __restrict__ lin_w,
                                              const float* __restrict__ conv_b,
                                              const float* __restrict__ lin_b,
                                              unsigned short* __restrict__ wfrag,
                                              float* __restrict__ biasf) {
  __shared__ float lwT[128 * 128];  // 64 KB
  for (int e = threadIdx.x; e < 16384; e += 256) {
    int co = e >> 7, t = e & 127;
    lwT[t * 128 + (co ^ (t & 31))] = lin_w[e];
  }
  __syncthreads();

  int id = blockIdx.x * 256 + threadIdx.x;
  const int NW = TAPS * 4 * 8 * 64;  // 55296
  if (id < NW) {
    int l  = id & 63;
    int s  = (id >> 6) & 7;
    int nt = (id >> 9) & 3;
    int k  = id >> 11;
    int ci0 = s * 16 + (l >> 5) * 8;
    int co  = nt * 32 + (l & 31);
    const float* cw = conv_w + ((size_t)(k * 128 + ci0)) * 128;
    float acc[8] = {0, 0, 0, 0, 0, 0, 0, 0};
    for (int t = 0; t < 128; ++t) {
      float lv = lwT[t * 128 + (co ^ (t & 31))];
#pragma unroll
      for (int j = 0; j < 8; ++j) acc[j] += cw[j * 128 + t] * lv;
    }
    uint4 v;
    v.x = f2bf(acc[0]) | (f2bf(acc[1]) << 16);
    v.y = f2bf(acc[2]) | (f2bf(acc[3]) << 16);
    v.z = f2bf(acc[4]) | (f2bf(acc[5]) << 16);
    v.w = f2bf(acc[6]) | (f2bf(acc[7]) << 16);
    *(uint4*)(wfrag + (size_t)id * 8) = v;
  } else if (id < NW + 128) {
    int co = id - NW;
    float s = lin_b[co];
    for (int t = 0; t < 128; ++t) s += conv_b[t] * lwT[t * 128 + (co ^ (t & 31))];
    biasf[co] = s;
  }
}

// ---------------- fused gather-GEMM + LayerNorm ----------------
// 512 thr = 8 waves; wave w owns rows [blk*256 + w*32, +32), ALL 128 cols.
// Round-0 schedule (best measured): A gathered post-barrier in the same tap,
// B LDS double-buffer via global_load_lds with 1-tap lookahead, raw s_barrier
// + manual vmcnt(4) (never drain to 0 mid-loop). This round's changes:
//   * A-gathers via buffer_load sc0 (L1-bypass) -> MSHR-cap experiment.
//   * nid loads from transposed nidxT (2 lines/wave-tap instead of 32),
//     via unified (rowstride, tapstride) addressing, ws-guarded on host.
__global__ __launch_bounds__(512, 4) void k_main(const unsigned short* __restrict__ featsB,
                                                 const int* __restrict__ ntab,
                                                 const int nrs, const int nts,
                                                 const unsigned short* __restrict__ wfrag,
                                                 const float* __restrict__ biasf,
                                                 const float* __restrict__ lnw,
                                                 const float* __restrict__ lnb,
                                                 float* __restrict__ out) {
  __shared__ unsigned short ldsB[2][16384];  // 2 x 32 KB

  const int tid = threadIdx.x;
  const int l   = tid & 63;
  const int w   = tid >> 6;
  const int l31 = l & 31;
  const int lh  = l >> 5;
  const int row0w = blockIdx.x * 256 + w * 32;
  const int gr  = row0w + l31;
  const int grc = (gr < N_ROWS) ? gr : 0;
  const int* np = ntab + (size_t)grc * nrs;

#if GATHER_SC0
  __amdgpu_buffer_rsrc_t rsrc = __builtin_amdgcn_make_buffer_rsrc(
      (void*)featsB, (short)0, N_ROWS * C_DIM * 2, 0x00020000);
#endif

  floatx16 acc0 = {0.f}, acc1 = {0.f}, acc2 = {0.f}, acc3 = {0.f};

  // prologue: stage B(0) into buf0
  {
    const unsigned short* src = wfrag + (size_t)tid * 8;
    unsigned short* dst = &ldsB[0][w * 512];
#pragma unroll
    for (int r = 0; r < 4; ++r) glds16(src + r * 4096, dst + r * 4096);
  }
  int nid = np[0];

  for (int k = 0; k < TAPS; ++k) {
    const int cur = k & 1;
    if (k + 1 < TAPS) {
      // prefetch B(k+1) into the other buffer (all waves done reading it:
      // end-of-iter barrier of k-1)
      const unsigned short* src = wfrag + (size_t)(k + 1) * 16384 + (size_t)tid * 8;
      unsigned short* dst = &ldsB[cur ^ 1][w * 512];
#pragma unroll
      for (int r = 0; r < 4; ++r) glds16(src + r * 4096, dst + r * 4096);
      __builtin_amdgcn_s_waitcnt(0xF74);  // vmcnt(4): B(k) landed, B(k+1) in flight
    } else {
      __builtin_amdgcn_s_waitcnt(0xF70);  // vmcnt(0)
    }
    __builtin_amdgcn_s_barrier();         // raw: no compiler vmcnt(0) drain

    // A fragments for tap k (per-lane gather, 32 random rows / wave)
#if GATHER_SC0
    const int voff = ((int)(unsigned)nid << 8) + (lh << 4);  // nid*256 + lh*16 bytes
    short8 a0 = ld16sc0(rsrc, voff);
    short8 a1 = ld16sc0(rsrc, voff + 32);
    short8 a2 = ld16sc0(rsrc, voff + 64);
    short8 a3 = ld16sc0(rsrc, voff + 96);
    short8 a4 = ld16sc0(rsrc, voff + 128);
    short8 a5 = ld16sc0(rsrc, voff + 160);
    short8 a6 = ld16sc0(rsrc, voff + 192);
    short8 a7 = ld16sc0(rsrc, voff + 224);
#else
    const short8* ap = (const short8*)(featsB + (size_t)(unsigned)nid * 128 + lh * 8);
    short8 a0 = ap[0],  a1 = ap[2],  a2 = ap[4],  a3 = ap[6];
    short8 a4 = ap[8],  a5 = ap[10], a6 = ap[12], a7 = ap[14];
#endif
    int nid_next = (k + 1 < TAPS) ? np[(k + 1) * nts] : 0;

    const unsigned short* bb = &ldsB[cur][l * 8];
#pragma unroll
    for (int s = 0; s < 8; ++s) {
      short8 av = (s == 0) ? a0 : (s == 1) ? a1 : (s == 2) ? a2 : (s == 3) ? a3
                : (s == 4) ? a4 : (s == 5) ? a5 : (s == 6) ? a6 : a7;
      short8 b0 = *(const short8*)(bb + (0 * 8 + s) * 512);
      short8 b1 = *(const short8*)(bb + (1 * 8 + s) * 512);
      short8 b2 = *(const short8*)(bb + (2 * 8 + s) * 512);
      short8 b3 = *(const short8*)(bb + (3 * 8 + s) * 512);
      acc0 = __builtin_amdgcn_mfma_f32_32x32x16_bf16(av, b0, acc0, 0, 0, 0);
      acc1 = __builtin_amdgcn_mfma_f32_32x32x16_bf16(av, b1, acc1, 0, 0, 0);
      acc2 = __builtin_amdgcn_mfma_f32_32x32x16_bf16(av, b2, acc2, 0, 0, 0);
      acc3 = __builtin_amdgcn_mfma_f32_32x32x16_bf16(av, b3, acc3, 0, 0, 0);
    }
    __builtin_amdgcn_s_barrier();  // all reads of buf[cur] done before overwrite
    nid = nid_next;
  }

  // ---- epilogue: bias + in-wave LayerNorm + store ----
  float b0 = biasf[l31], b1 = biasf[32 + l31], b2 = biasf[64 + l31], b3 = biasf[96 + l31];
  float g0 = lnw[l31],   g1 = lnw[32 + l31],   g2 = lnw[64 + l31],   g3 = lnw[96 + l31];
  float c0 = lnb[l31],   c1 = lnb[32 + l31],   c2 = lnb[64 + l31],   c3 = lnb[96 + l31];

#pragma unroll
  for (int r = 0; r < 16; ++r) {
    float x0 = acc0[r] + b0, x1 = acc1[r] + b1, x2 = acc2[r] + b2, x3 = acc3[r] + b3;
    float s = x0 + x1 + x2 + x3;
    float q = x0 * x0 + x1 * x1 + x2 * x2 + x3 * x3;
#pragma unroll
    for (int off = 16; off >= 1; off >>= 1) {
      s += __shfl_xor(s, off, 64);
      q += __shfl_xor(q, off, 64);
    }
    float mu  = s * (1.0f / 128.0f);
    float var = q * (1.0f / 128.0f) - mu * mu;
    float rs  = rsqrtf(var + EPS);
    int row   = (r & 3) + 8 * (r >> 2) + 4 * lh;  // 32x32 C/D row map
    int grow  = row0w + row;
    if (grow < N_ROWS) {
      float* o = out + (size_t)grow * 128;
      o[l31]      = (x0 - mu) * rs * g0 + c0;
      o[32 + l31] = (x1 - mu) * rs * g1 + c1;
      o[64 + l31] = (x2 - mu) * rs * g2 + c2;
      o[96 + l31] = (x3 - mu) * rs * g3 + c3;
    }
  }
}

extern "C" void kernel_launch(void* const* d_in, const int* in_sizes, int n_in,
                              void* d_out, int out_size, void* d_ws, size_t ws_size,
                              hipStream_t stream) {
  const float* feats  = (const float*)d_in[0];
  const int*   nidx   = (const int*)d_in[1];
  const float* conv_w = (const float*)d_in[2];
  const float* conv_b = (const float*)d_in[3];
  const float* lin_w  = (const float*)d_in[4];
  const float* lin_b  = (const float*)d_in[5];
  const float* ln_w   = (const float*)d_in[6];
  const float* ln_b   = (const float*)d_in[7];
  float* out = (float*)d_out;

  unsigned short* featsB = (unsigned short*)d_ws;                       // 51,200,000 B
  unsigned short* wfrag  = (unsigned short*)((char*)d_ws + 51200000);   //    884,736 B
  float*          biasf  = (float*)((char*)d_ws + 51200000 + 884736);   //        512 B
  int*            nidxT  = (int*)((char*)d_ws + 51200000 + 884736 + 512); // 21,600,000 B

  const size_t ws_need_tr = 51200000ULL + 884736ULL + 512ULL + 21600000ULL;
  const bool use_tr = (ws_size >= ws_need_tr);

  int n8 = N_ROWS * C_DIM / 8;  // 3,200,000
  k_cast<<<(n8 + 255) / 256, 256, 0, stream>>>(feats, featsB, n8);
  k_fold<<<(TAPS * 2048 + 128 + 255) / 256, 256, 0, stream>>>(conv_w, lin_w, conv_b, lin_b,
                                                              wfrag, biasf);
  if (use_tr) k_tr<<<N_ROWS / 64, 256, 0, stream>>>(nidx, nidxT);

  k_main<<<(N_ROWS + 255) / 256, 512, 0, stream>>>(
      featsB,
      use_tr ? (const int*)nidxT : nidx,
      use_tr ? 1 : TAPS,          // row stride (ints)
      use_tr ? N_ROWS : 1,        // tap stride (ints)
      wfrag, biasf, ln_w, ln_b, out);
}

// Round 6
// 481.029 us; speedup vs baseline: 1.0788x; 1.0639x over previous
//
#include <hip/hip_runtime.h>
#include <hip/hip_bf16.h>
#include <stdint.h>

#define N_ROWS 200000
#define C_DIM  128
#define TAPS   27
#define EPS    1e-5f

typedef __attribute__((ext_vector_type(8)))  short  short8;
typedef __attribute__((ext_vector_type(16))) float  floatx16;

// ---- gather path: sc0 buffer loads (r3: neutral perf, saves 8 VGPRs; keep) ----
#if __has_builtin(__builtin_amdgcn_make_buffer_rsrc) && __has_builtin(__builtin_amdgcn_raw_buffer_load_b128)
#define GATHER_SC0 1
#else
#define GATHER_SC0 0
#endif

#define SBAR()  __builtin_amdgcn_s_barrier()
#define SCHED() __builtin_amdgcn_sched_barrier(0)

__device__ __forceinline__ unsigned int f2bf(float f) {
  union { float f; unsigned int u; } v; v.f = f;
  unsigned int r = v.u + 0x7FFFu + ((v.u >> 16) & 1u);   // RNE, inputs finite
  return r >> 16;
}

__device__ __forceinline__ void glds16(const unsigned short* g, unsigned short* l) {
  __builtin_amdgcn_global_load_lds(
      (const __attribute__((address_space(1))) unsigned int*)g,
      (__attribute__((address_space(3))) unsigned int*)l, 16, 0, 0);
}

#if GATHER_SC0
__device__ __forceinline__ short8 ld16sc0(__amdgpu_buffer_rsrc_t r, int voff) {
  return __builtin_bit_cast(short8,
      __builtin_amdgcn_raw_buffer_load_b128(r, voff, 0, 1));
}
#endif

// ---------------- feats fp32 -> bf16 ----------------
__global__ __launch_bounds__(256) void k_cast(const float* __restrict__ in,
                                              unsigned short* __restrict__ out, int n8) {
  int i = blockIdx.x * 256 + threadIdx.x;
  if (i >= n8) return;
  const float4* p = (const float4*)in + (size_t)i * 2;
  float4 a = p[0], b = p[1];
  uint4 v;
  v.x = f2bf(a.x) | (f2bf(a.y) << 16);
  v.y = f2bf(a.z) | (f2bf(a.w) << 16);
  v.z = f2bf(b.x) | (f2bf(b.y) << 16);
  v.w = f2bf(b.z) | (f2bf(b.w) << 16);
  *(uint4*)(out + (size_t)i * 8) = v;
}

// ---------------- nidx [N][27] -> nidxT [27][N] ----------------
__global__ __launch_bounds__(256) void k_tr(const int* __restrict__ in,
                                            int* __restrict__ outT) {
  __shared__ int t[1728];
  const int tile = blockIdx.x;                 // 3125 tiles x 64 rows (exact)
  const int* src = in + (size_t)tile * 1728;
  for (int e = threadIdx.x; e < 1728; e += 256) t[e] = src[e];
  __syncthreads();
  const int base = tile * 64;
  for (int o = threadIdx.x; o < 1728; o += 256) {
    int k = o >> 6, r = o & 63;
    outT[(size_t)k * N_ROWS + base + r] = t[r * 27 + k];
  }
}

// ---- fold Linear into conv weights; emit MFMA B-fragment layout ----
// wfrag[k][h(2)][nt(4)][sh(4)][lane(64)][j(8)] (bf16): each K=64 HALF of a tap
// (8192 shorts = 16 KB) contiguous for glds staging.
//   s = h*4+sh ; kk_global = s*16 + (l>>5)*8 + j ; co = nt*32 + (l&31)
__global__ __launch_bounds__(256) void k_fold(const float* __restrict__ conv_w,
                                              const float* __restrict__ lin_w,
                                              const float* __restrict__ conv_b,
                                              const float* __restrict__ lin_b,
                                              unsigned short* __restrict__ wfrag,
                                              float* __restrict__ biasf) {
  __shared__ float lwT[128 * 128];  // 64 KB
  for (int e = threadIdx.x; e < 16384; e += 256) {
    int co = e >> 7, t = e & 127;
    lwT[t * 128 + (co ^ (t & 31))] = lin_w[e];
  }
  __syncthreads();

  int id = blockIdx.x * 256 + threadIdx.x;
  const int NW = TAPS * 2 * 4 * 4 * 64;  // 55296
  if (id < NW) {
    int l  = id & 63;
    int sh = (id >> 6) & 3;
    int nt = (id >> 8) & 3;
    int h  = (id >> 10) & 1;
    int k  = id >> 11;
    int s  = h * 4 + sh;
    int ci0 = s * 16 + (l >> 5) * 8;
    int co  = nt * 32 + (l & 31);
    const float* cw = conv_w + ((size_t)(k * 128 + ci0)) * 128;
    float acc[8] = {0, 0, 0, 0, 0, 0, 0, 0};
    for (int t = 0; t < 128; ++t) {
      float lv = lwT[t * 128 + (co ^ (t & 31))];
#pragma unroll
      for (int j = 0; j < 8; ++j) acc[j] += cw[j * 128 + t] * lv;
    }
    uint4 v;
    v.x = f2bf(acc[0]) | (f2bf(acc[1]) << 16);
    v.y = f2bf(acc[2]) | (f2bf(acc[3]) << 16);
    v.z = f2bf(acc[4]) | (f2bf(acc[5]) << 16);
    v.w = f2bf(acc[6]) | (f2bf(acc[7]) << 16);
    *(uint4*)(wfrag + (size_t)id * 8) = v;
  } else if (id < NW + 128) {
    int co = id - NW;
    float s = lin_b[co];
    for (int t = 0; t < 128; ++t) s += conv_b[t] * lwT[t * 128 + (co ^ (t & 31))];
    biasf[co] = s;
  }
}

// ---------------- fused gather-GEMM + LayerNorm ----------------
// r5 = r4 geometry (4 waves/block, 128 rows, 2x16KB LDS dbuf -> 4 blocks/CU)
// with RACE FIX per rule #18: sched_barrier(0) immediately BEFORE every
// s_barrier, so register-only MFMAs (and their compiler-attached vmcnt waits)
// cannot sink across a barrier. Invariant restored: a wave arriving at the
// odd-half barrier has executed its even-half a0-wait, which (in-order vmcnt
// retirement) retired its buf1 glds -> all waves' buf1 data landed before any
// wave reads buf1. Even half keeps the explicit inline vmcnt(4) as in r0.
__global__ __launch_bounds__(256, 4) void k_main(const unsigned short* __restrict__ featsB,
                                                 const int* __restrict__ ntab,
                                                 const int nrs, const int nts,
                                                 const unsigned short* __restrict__ wfrag,
                                                 const float* __restrict__ biasf,
                                                 const float* __restrict__ lnw,
                                                 const float* __restrict__ lnb,
                                                 float* __restrict__ out) {
  __shared__ unsigned short ldsB[2][8192];  // 2 x 16 KB

  const int tid = threadIdx.x;
  const int l   = tid & 63;
  const int w   = tid >> 6;          // 0..3
  const int l31 = l & 31;
  const int lh  = l >> 5;
  const int row0w = blockIdx.x * 128 + w * 32;
  const int gr  = row0w + l31;
  const int grc = (gr < N_ROWS) ? gr : 0;
  const int* np = ntab + (size_t)grc * nrs;

#if GATHER_SC0
  __amdgpu_buffer_rsrc_t rsrc = __builtin_amdgcn_make_buffer_rsrc(
      (void*)featsB, (short)0, N_ROWS * C_DIM * 2, 0x00020000);
#endif

  floatx16 acc0 = {0.f}, acc1 = {0.f}, acc2 = {0.f}, acc3 = {0.f};

  // prologue: stage H(0) (tap0 half0) into buf0
  {
    const unsigned short* src = wfrag + (size_t)tid * 8;
    unsigned short* dst = &ldsB[0][w * 512];
#pragma unroll
    for (int r = 0; r < 4; ++r) glds16(src + r * 2048, dst + r * 2048);
  }
  int nid = np[0];
  short8 a0, a1, a2, a3, a4, a5, a6, a7;

  for (int t = 0; t < TAPS; ++t) {
    // ================= even half: K 0..63, reads buf0 =================
    {
      // stage H(2t+1) (this tap's half1) into buf1
      const unsigned short* src = wfrag + (size_t)(2 * t + 1) * 8192 + (size_t)tid * 8;
      unsigned short* dst = &ldsB[1][w * 512];
#pragma unroll
      for (int r = 0; r < 4; ++r) glds16(src + r * 2048, dst + r * 2048);
    }
    SCHED();                             // pin glds above the count
    __builtin_amdgcn_s_waitcnt(0xF74);   // vmcnt(4): H(2t) landed; H(2t+1) in flight
    SCHED();
    SBAR();                              // B1: buf0 valid for all waves
    SCHED();

    // A gathers for tap t (full row; a4..a7 consumed next half)
#if GATHER_SC0
    const int voff = ((int)(unsigned)nid << 8) + (lh << 4);
    a0 = ld16sc0(rsrc, voff);
    a1 = ld16sc0(rsrc, voff + 32);
    a2 = ld16sc0(rsrc, voff + 64);
    a3 = ld16sc0(rsrc, voff + 96);
    a4 = ld16sc0(rsrc, voff + 128);
    a5 = ld16sc0(rsrc, voff + 160);
    a6 = ld16sc0(rsrc, voff + 192);
    a7 = ld16sc0(rsrc, voff + 224);
#else
    const short8* ap = (const short8*)(featsB + (size_t)(unsigned)nid * 128 + lh * 8);
    a0 = ap[0];  a1 = ap[2];  a2 = ap[4];  a3 = ap[6];
    a4 = ap[8];  a5 = ap[10]; a6 = ap[12]; a7 = ap[14];
#endif
    int nid_next = (t + 1 < TAPS) ? np[(t + 1) * nts] : 0;

    {
      const unsigned short* bb = &ldsB[0][l * 8];
#pragma unroll
      for (int sh = 0; sh < 4; ++sh) {
        short8 av = (sh == 0) ? a0 : (sh == 1) ? a1 : (sh == 2) ? a2 : a3;
        short8 b0 = *(const short8*)(bb + (0 * 4 + sh) * 512);
        short8 b1 = *(const short8*)(bb + (1 * 4 + sh) * 512);
        short8 b2 = *(const short8*)(bb + (2 * 4 + sh) * 512);
        short8 b3 = *(const short8*)(bb + (3 * 4 + sh) * 512);
        acc0 = __builtin_amdgcn_mfma_f32_32x32x16_bf16(av, b0, acc0, 0, 0, 0);
        acc1 = __builtin_amdgcn_mfma_f32_32x32x16_bf16(av, b1, acc1, 0, 0, 0);
        acc2 = __builtin_amdgcn_mfma_f32_32x32x16_bf16(av, b2, acc2, 0, 0, 0);
        acc3 = __builtin_amdgcn_mfma_f32_32x32x16_bf16(av, b3, acc3, 0, 0, 0);
      }
    }
    SCHED();   // RACE FIX: even-half MFMAs + their vmcnt/lgkm waits stay above B2
    SBAR();    // B2: all reads of buf0 done (odd glds will overwrite)
    SCHED();

    // ================= odd half: K 64..127, reads buf1 =================
    if (t + 1 < TAPS) {
      // stage H(2t+2) (next tap's half0) into buf0
      const unsigned short* src = wfrag + (size_t)(2 * t + 2) * 8192 + (size_t)tid * 8;
      unsigned short* dst = &ldsB[0][w * 512];
#pragma unroll
      for (int r = 0; r < 4; ++r) glds16(src + r * 2048, dst + r * 2048);
    }
    // no inline vmcnt: each wave's even-half a0-wait (pinned above B2 by the
    // fence) already retired its buf1 glds; barrier makes that global.
    SCHED();
    SBAR();    // B3
    SCHED();
    {
      const unsigned short* bb = &ldsB[1][l * 8];
#pragma unroll
      for (int sh = 0; sh < 4; ++sh) {
        short8 av = (sh == 0) ? a4 : (sh == 1) ? a5 : (sh == 2) ? a6 : a7;
        short8 b0 = *(const short8*)(bb + (0 * 4 + sh) * 512);
        short8 b1 = *(const short8*)(bb + (1 * 4 + sh) * 512);
        short8 b2 = *(const short8*)(bb + (2 * 4 + sh) * 512);
        short8 b3 = *(const short8*)(bb + (3 * 4 + sh) * 512);
        acc0 = __builtin_amdgcn_mfma_f32_32x32x16_bf16(av, b0, acc0, 0, 0, 0);
        acc1 = __builtin_amdgcn_mfma_f32_32x32x16_bf16(av, b1, acc1, 0, 0, 0);
        acc2 = __builtin_amdgcn_mfma_f32_32x32x16_bf16(av, b2, acc2, 0, 0, 0);
        acc3 = __builtin_amdgcn_mfma_f32_32x32x16_bf16(av, b3, acc3, 0, 0, 0);
      }
    }
    if (t + 1 < TAPS) {
      SCHED(); // RACE FIX: odd-half MFMAs + waits stay above B4
      SBAR();  // B4: all reads of buf1 done (next even glds will overwrite)
      SCHED();
    }
    nid = nid_next;
  }

  // ---- epilogue: bias + in-wave LayerNorm + store ----
  float b0 = biasf[l31], b1 = biasf[32 + l31], b2 = biasf[64 + l31], b3 = biasf[96 + l31];
  float g0 = lnw[l31],   g1 = lnw[32 + l31],   g2 = lnw[64 + l31],   g3 = lnw[96 + l31];
  float c0 = lnb[l31],   c1 = lnb[32 + l31],   c2 = lnb[64 + l31],   c3 = lnb[96 + l31];

#pragma unroll
  for (int r = 0; r < 16; ++r) {
    float x0 = acc0[r] + b0, x1 = acc1[r] + b1, x2 = acc2[r] + b2, x3 = acc3[r] + b3;
    float s = x0 + x1 + x2 + x3;
    float q = x0 * x0 + x1 * x1 + x2 * x2 + x3 * x3;
#pragma unroll
    for (int off = 16; off >= 1; off >>= 1) {
      s += __shfl_xor(s, off, 64);
      q += __shfl_xor(q, off, 64);
    }
    float mu  = s * (1.0f / 128.0f);
    float var = q * (1.0f / 128.0f) - mu * mu;
    float rs  = rsqrtf(var + EPS);
    int row   = (r & 3) + 8 * (r >> 2) + 4 * lh;  // 32x32 C/D row map
    int grow  = row0w + row;
    if (grow < N_ROWS) {
      float* o = out + (size_t)grow * 128;
      o[l31]      = (x0 - mu) * rs * g0 + c0;
      o[32 + l31] = (x1 - mu) * rs * g1 + c1;
      o[64 + l31] = (x2 - mu) * rs * g2 + c2;
      o[96 + l31] = (x3 - mu) * rs * g3 + c3;
    }
  }
}

extern "C" void kernel_launch(void* const* d_in, const int* in_sizes, int n_in,
                              void* d_out, int out_size, void* d_ws, size_t ws_size,
                              hipStream_t stream) {
  const float* feats  = (const float*)d_in[0];
  const int*   nidx   = (const int*)d_in[1];
  const float* conv_w = (const float*)d_in[2];
  const float* conv_b = (const float*)d_in[3];
  const float* lin_w  = (const float*)d_in[4];
  const float* lin_b  = (const float*)d_in[5];
  const float* ln_w   = (const float*)d_in[6];
  const float* ln_b   = (const float*)d_in[7];
  float* out = (float*)d_out;

  unsigned short* featsB = (unsigned short*)d_ws;                       // 51,200,000 B
  unsigned short* wfrag  = (unsigned short*)((char*)d_ws + 51200000);   //    884,736 B
  float*          biasf  = (float*)((char*)d_ws + 51200000 + 884736);   //        512 B
  int*            nidxT  = (int*)((char*)d_ws + 51200000 + 884736 + 512); // 21,600,000 B

  const size_t ws_need_tr = 51200000ULL + 884736ULL + 512ULL + 21600000ULL;
  const bool use_tr = (ws_size >= ws_need_tr);

  int n8 = N_ROWS * C_DIM / 8;  // 3,200,000
  k_cast<<<(n8 + 255) / 256, 256, 0, stream>>>(feats, featsB, n8);
  k_fold<<<(TAPS * 2048 + 128 + 255) / 256, 256, 0, stream>>>(conv_w, lin_w, conv_b, lin_b,
                                                              wfrag, biasf);
  if (use_tr) k_tr<<<N_ROWS / 64, 256, 0, stream>>>(nidx, nidxT);

  k_main<<<(N_ROWS + 127) / 128, 256, 0, stream>>>(
      featsB,
      use_tr ? (const int*)nidxT : nidx,
      use_tr ? 1 : TAPS,          // row stride (ints)
      use_tr ? N_ROWS : 1,        // tap stride (ints)
      wfrag, biasf, ln_w, ln_b, out);
}